// Round 12
// baseline (291.477 us; speedup 1.0000x reference)
//
#include <hip/hip_runtime.h>

typedef unsigned short ushort_t;
typedef unsigned int uint_t;
typedef __attribute__((ext_vector_type(8))) short bf16x8;
typedef __attribute__((ext_vector_type(4))) float f32x4;

#define EPSV 1e-5f
#define LOG2E 1.4426950408889634f
#define QSC (0.17677669529663687f * LOG2E)   // (1/sqrt(32)) * log2(e)

__device__ __forceinline__ float u2f(uint_t x) { return __builtin_bit_cast(float, x); }
__device__ __forceinline__ uint_t f2u(float x) { return __builtin_bit_cast(uint_t, x); }
__device__ __forceinline__ float bflo(uint_t u) { return u2f(u << 16); }
__device__ __forceinline__ float bfhi(uint_t u) { return u2f(u & 0xFFFF0000u); }
__device__ __forceinline__ ushort_t f2bf(float f) {
    uint_t x = f2u(f);
    x += 0x7FFFu + ((x >> 16) & 1u);   // RNE
    return (ushort_t)(x >> 16);
}
__device__ __forceinline__ uint_t cvtpk(float lo, float hi) {
    uint_t r;
    asm("v_cvt_pk_bf16_f32 %0, %1, %2" : "=v"(r) : "v"(lo), "v"(hi));
    return r;
}
__device__ __forceinline__ float exp2v(float x) {
    float r;
    asm("v_exp_f32 %0, %1" : "=v"(r) : "v"(x));
    return r;
}
__device__ __forceinline__ float rcpv(float x) {
    float r;
    asm("v_rcp_f32 %0, %1" : "=v"(r) : "v"(x));
    return r;
}
__device__ __forceinline__ f32x4 mfma16(bf16x8 a, bf16x8 b, f32x4 c) {
    return __builtin_amdgcn_mfma_f32_16x16x32_bf16(a, b, c, 0, 0, 0);
}
__device__ __forceinline__ float wsum(float v) {
#pragma unroll
    for (int m = 32; m >= 1; m >>= 1) v += __shfl_xor(v, m, 64);
    return v;
}
// XOR swizzles (bijective; flip bits 3-5 of the linear ush index; keep 8-ush
// chunks intact so b128/uint2 accesses stay contiguous & aligned).
__device__ __forceinline__ int swz32(int row, int col) {   // [256][32] tiles
    return (row * 32 + col) ^ ((row & 7) << 3);
}
__device__ __forceinline__ int swzT(int c, int i) {        // [32][256] tiles
    return c * 256 + (i ^ ((c & 7) << 3));
}

// -------- K_pre: fused {LayerNorm(m) | LayerNorm(z)@Wb | weight transpose} --------
#define NB_LN 16384
#define NB_PB 1024
__global__ __launch_bounds__(256) void k_pre(const float* __restrict__ m,
                                             const float* __restrict__ ln_m_g,
                                             const float* __restrict__ ln_m_b,
                                             const float* __restrict__ z,
                                             const float* __restrict__ ln_z_g,
                                             const float* __restrict__ ln_z_b,
                                             const float* __restrict__ Wb,
                                             const float* __restrict__ Wq, const float* __restrict__ Wk,
                                             const float* __restrict__ Wv, const float* __restrict__ Wg,
                                             const float* __restrict__ Wo,
                                             ushort_t* __restrict__ mn,
                                             float* __restrict__ pb,
                                             ushort_t* __restrict__ wtT, ushort_t* __restrict__ woT) {
    __shared__ float wb_lds[1024];
    const int bid = blockIdx.x, t = threadIdx.x;

    if (bid < NB_LN) {
        const int lane = t & 63;
        const int row  = bid * 4 + (t >> 6);
        const float4 x = *(const float4*)(m + (size_t)row * 256 + lane * 4);
        const float mu = wsum(x.x + x.y + x.z + x.w) * (1.f / 256.f);
        const float dx = x.x - mu, dy = x.y - mu, dz = x.z - mu, dw = x.w - mu;
        const float var = wsum(dx * dx + dy * dy + dz * dz + dw * dw) * (1.f / 256.f);
        const float rs = rsqrtf(var + EPSV);
        const float4 gg = *(const float4*)(ln_m_g + lane * 4);
        const float4 bb = *(const float4*)(ln_m_b + lane * 4);
        ushort4 o;
        o.x = f2bf(dx * rs * gg.x + bb.x);
        o.y = f2bf(dy * rs * gg.y + bb.y);
        o.z = f2bf(dz * rs * gg.z + bb.z);
        o.w = f2bf(dw * rs * gg.w + bb.w);
        *(ushort4*)(mn + (size_t)row * 256 + lane * 4) = o;
    } else if (bid < NB_LN + NB_PB) {
        const int pbid = bid - NB_LN;
        const int w = t >> 6, l = t & 63;
        const int l16 = l & 15, gq = l >> 4;
        *(float4*)&wb_lds[t * 4] = *(const float4*)(Wb + t * 4);
        __syncthreads();

        const int row = pbid * 64 + w * 16 + l16;
        const float* zr = z + (size_t)row * 128;
        float v[32];
        float s1 = 0.f, s2 = 0.f;
#pragma unroll
        for (int ks = 0; ks < 4; ++ks) {
            const float4 a0 = *(const float4*)(zr + ks * 32 + gq * 8);
            const float4 a1 = *(const float4*)(zr + ks * 32 + gq * 8 + 4);
            v[ks * 8 + 0] = a0.x; v[ks * 8 + 1] = a0.y; v[ks * 8 + 2] = a0.z; v[ks * 8 + 3] = a0.w;
            v[ks * 8 + 4] = a1.x; v[ks * 8 + 5] = a1.y; v[ks * 8 + 6] = a1.z; v[ks * 8 + 7] = a1.w;
        }
#pragma unroll
        for (int j = 0; j < 32; ++j) { s1 += v[j]; s2 += v[j] * v[j]; }
        s1 += __shfl_xor(s1, 16, 64); s1 += __shfl_xor(s1, 32, 64);
        s2 += __shfl_xor(s2, 16, 64); s2 += __shfl_xor(s2, 32, 64);
        const float mu = s1 * (1.f / 128.f);
        const float var = s2 * (1.f / 128.f) - mu * mu;
        const float rs = rsqrtf(var + EPSV);

        f32x4 acc = (f32x4){0.f, 0.f, 0.f, 0.f};
#pragma unroll
        for (int ks = 0; ks < 4; ++ks) {
            const float4 g0 = *(const float4*)(ln_z_g + ks * 32 + gq * 8);
            const float4 g1 = *(const float4*)(ln_z_g + ks * 32 + gq * 8 + 4);
            const float4 b0 = *(const float4*)(ln_z_b + ks * 32 + gq * 8);
            const float4 b1 = *(const float4*)(ln_z_b + ks * 32 + gq * 8 + 4);
            const float xn0 = (v[ks * 8 + 0] - mu) * rs * g0.x + b0.x;
            const float xn1 = (v[ks * 8 + 1] - mu) * rs * g0.y + b0.y;
            const float xn2 = (v[ks * 8 + 2] - mu) * rs * g0.z + b0.z;
            const float xn3 = (v[ks * 8 + 3] - mu) * rs * g0.w + b0.w;
            const float xn4 = (v[ks * 8 + 4] - mu) * rs * g1.x + b1.x;
            const float xn5 = (v[ks * 8 + 5] - mu) * rs * g1.y + b1.y;
            const float xn6 = (v[ks * 8 + 6] - mu) * rs * g1.z + b1.z;
            const float xn7 = (v[ks * 8 + 7] - mu) * rs * g1.w + b1.w;
            uint4 pk;
            pk.x = cvtpk(xn0, xn1); pk.y = cvtpk(xn2, xn3);
            pk.z = cvtpk(xn4, xn5); pk.w = cvtpk(xn6, xn7);
            const bf16x8 af = __builtin_bit_cast(bf16x8, pk);
            ushort_t wf[8];
#pragma unroll
            for (int j = 0; j < 8; ++j)
                wf[j] = (l16 < 8) ? f2bf(wb_lds[(ks * 32 + gq * 8 + j) * 8 + l16]) : (ushort_t)0;
            const bf16x8 bf_ = *(const bf16x8*)wf;
            acc = mfma16(af, bf_, acc);
        }
        if (l16 < 8) {
            const int orow = pbid * 64 + w * 16 + gq * 4;
            f32x4 o;
            o[0] = acc[0] * LOG2E; o[1] = acc[1] * LOG2E;
            o[2] = acc[2] * LOG2E; o[3] = acc[3] * LOG2E;
            *(f32x4*)(pb + (size_t)l16 * 65536 + orow) = o;
        }
    } else {
        const int k = bid - (NB_LN + NB_PB);
        const int h = t >> 5, c = t & 31;
        wtT[(size_t)(h * 128 +   0 + c) * 256 + k] = f2bf(Wq[k * 256 + t]);
        wtT[(size_t)(h * 128 +  32 + c) * 256 + k] = f2bf(Wk[k * 256 + t]);
        wtT[(size_t)(h * 128 +  64 + c) * 256 + k] = f2bf(Wv[k * 256 + t]);
        wtT[(size_t)(h * 128 +  96 + c) * 256 + k] = f2bf(Wg[k * 256 + t]);
        woT[(size_t)t * 256 + k] = f2bf(Wo[k * 256 + t]);
    }
}

// -------- K3: MFMA fused QKVG projection + attention (no-max softmax) + gate --------
// R8-passing skeleton (256 threads, __launch_bounds__(256,1) — min-waves MUST be 1:
// R7's content-identical (256,2) build NaN'd). This round: LDS 75.8K -> 50,176 B
// (gate in regs; swizzled stride-32 K/Q/P; swizzled vT) => 3 blocks/CU = 3 waves/SIMD.
// blockIdx decode: n = bid & 255, h = bid >> 8 => all 8 heads of one n land on the
// same XCD (XCD = bid % 8 = n % 8), so mn[n] is fetched from HBM once, reused from L2.
__global__ __launch_bounds__(256, 1) void k_attn(const ushort_t* __restrict__ mn,
                                                 const ushort_t* __restrict__ wtT,
                                                 const float* __restrict__ pb,
                                                 const int* __restrict__ msa_mask,
                                                 const float* __restrict__ bg,
                                                 ushort_t* __restrict__ ao) {
    __shared__ ushort_t k_s[8192];   // K [j][c] swz32; epilogue: gated-output [c][i] swzT
    __shared__ ushort_t qp_s[8192];  // q [i][c] swz32; Phase B: per-wave P; epilogue: gateT [c][i] swzT
    __shared__ ushort_t vT_s[8192];  // V^T [c][i] swzT
    __shared__ float maskb[256];

    const int t = threadIdx.x;
    const int n = blockIdx.x & 255, h = blockIdx.x >> 8;
    const int w = t >> 6, l = t & 63;
    const int l16 = l & 15, g = l >> 4;

    maskb[t] = msa_mask[n * 256 + t] ? 0.f : -1.5e9f;
    const float bg0 = bg[h * 32 + l16];
    const float bg1 = bg[h * 32 + 16 + l16];

    const ushort_t* mb = mn + (size_t)n * 65536;
    const ushort_t* wb = wtT + (size_t)h * 128 * 256;

    uint2 gpk[2][4];   // sigmoid gate, bf16-packed, in registers

    // ---- Phase A: qkvg[i][c] = mn[i][:] @ W[:,c] via MFMA ----
#pragma unroll
    for (int chalf = 0; chalf < 2; ++chalf) {
        f32x4 acc[4][4];
#pragma unroll
        for (int rt = 0; rt < 4; ++rt)
#pragma unroll
            for (int ct = 0; ct < 4; ++ct) acc[rt][ct] = (f32x4){0.f, 0.f, 0.f, 0.f};

#pragma unroll
        for (int ks = 0; ks < 8; ++ks) {
            bf16x8 a[4], b[4];
#pragma unroll
            for (int rt = 0; rt < 4; ++rt)
                a[rt] = *(const bf16x8*)(mb + (size_t)(w * 64 + rt * 16 + l16) * 256 + ks * 32 + g * 8);
#pragma unroll
            for (int ct = 0; ct < 4; ++ct)
                b[ct] = *(const bf16x8*)(wb + (size_t)(chalf * 64 + ct * 16 + l16) * 256 + ks * 32 + g * 8);
#pragma unroll
            for (int rt = 0; rt < 4; ++rt)
#pragma unroll
                for (int ct = 0; ct < 4; ++ct)
                    acc[rt][ct] = mfma16(a[rt], b[ct], acc[rt][ct]);
        }
        // epilogue: C-frag lane holds [row = g*4+r][col = l16]
#pragma unroll
        for (int ct = 0; ct < 4; ++ct) {
            const int mat = chalf * 2 + (ct >> 1);       // 0 q, 1 k, 2 v, 3 g
            const int cc = (ct & 1) * 16 + l16;
#pragma unroll
            for (int rt = 0; rt < 4; ++rt) {
                const int i0 = w * 64 + rt * 16 + g * 4;
                const f32x4 v = acc[rt][ct];
                if (mat == 0) {          // q: fold SCALE*log2e
#pragma unroll
                    for (int r = 0; r < 4; ++r) qp_s[swz32(i0 + r, cc)] = f2bf(v[r] * QSC);
                } else if (mat == 1) {   // k
#pragma unroll
                    for (int r = 0; r < 4; ++r) k_s[swz32(i0 + r, cc)] = f2bf(v[r]);
                } else if (mat == 2) {   // v -> transposed (swizzled)
                    *(uint2*)&vT_s[swzT(cc, i0)] = make_uint2(cvtpk(v[0], v[1]), cvtpk(v[2], v[3]));
                } else {                 // g -> sigmoid gate, kept in registers
                    const float bgc = (ct & 1) ? bg1 : bg0;
                    float gt[4];
#pragma unroll
                    for (int r = 0; r < 4; ++r)
                        gt[r] = rcpv(1.f + exp2v(-(v[r] + bgc) * LOG2E));
                    gpk[ct & 1][rt] = make_uint2(cvtpk(gt[0], gt[1]), cvtpk(gt[2], gt[3]));
                }
            }
        }
    }
    __syncthreads();   // bar1: q/k/vT visible to all waves

    // ---- Phase B: attention. Wave w owns rows i in [w*64, w*64+64). ----
    bf16x8 bq[4];
#pragma unroll
    for (int it = 0; it < 4; ++it)
        bq[it] = *(const bf16x8*)&qp_s[swz32(w * 64 + it * 16 + l16, g * 8)];
    // P buffer aliases this wave's own q rows (same-wave producer/consumer)

    const float* pbh = pb + (size_t)h * 65536;
    f32x4 oT[2][4];
#pragma unroll
    for (int ct = 0; ct < 2; ++ct)
#pragma unroll
        for (int it = 0; it < 4; ++it) oT[ct][it] = (f32x4){0.f, 0.f, 0.f, 0.f};
    float lsum[4] = {0.f, 0.f, 0.f, 0.f};

    // pipeline prologue: K/V fragments + pair-bias for jc=0
    bf16x8 ak[2], av[2];
    f32x4 pc0[4], pc1[4];
#pragma unroll
    for (int jt = 0; jt < 2; ++jt)
        ak[jt] = *(const bf16x8*)&k_s[swz32(jt * 16 + l16, g * 8)];
#pragma unroll
    for (int ct = 0; ct < 2; ++ct)
        av[ct] = *(const bf16x8*)&vT_s[swzT(ct * 16 + l16, g * 8)];
#pragma unroll
    for (int it = 0; it < 4; ++it) {
        const int i = w * 64 + it * 16 + l16;
        pc0[it] = *(const f32x4*)(pbh + (size_t)i * 256 + g * 4);
        pc1[it] = *(const f32x4*)(pbh + (size_t)i * 256 + 16 + g * 4);
    }

    for (int jc = 0; jc < 8; ++jc) {
        // prefetch next iteration's K/V fragments + pair-bias
        bf16x8 akn[2], avn[2];
        f32x4 pn0[4], pn1[4];
        if (jc < 7) {
            const int j0 = (jc + 1) * 32;
#pragma unroll
            for (int jt = 0; jt < 2; ++jt)
                akn[jt] = *(const bf16x8*)&k_s[swz32(j0 + jt * 16 + l16, g * 8)];
#pragma unroll
            for (int ct = 0; ct < 2; ++ct)
                avn[ct] = *(const bf16x8*)&vT_s[swzT(ct * 16 + l16, j0 + g * 8)];
#pragma unroll
            for (int it = 0; it < 4; ++it) {
                const int i = w * 64 + it * 16 + l16;
                pn0[it] = *(const f32x4*)(pbh + (size_t)i * 256 + j0 + g * 4);
                pn1[it] = *(const f32x4*)(pbh + (size_t)i * 256 + j0 + 16 + g * 4);
            }
        }

        // S^T = mfma(K, Q): lane holds S[j = jc*32 + jt*16 + g*4 + r][i = it*16 + l16]
        f32x4 st[2][4];
        __builtin_amdgcn_s_setprio(1);
#pragma unroll
        for (int jt = 0; jt < 2; ++jt)
#pragma unroll
            for (int it = 0; it < 4; ++it)
                st[jt][it] = mfma16(ak[jt], bq[it], (f32x4){0.f, 0.f, 0.f, 0.f});
        __builtin_amdgcn_s_setprio(0);

        const f32x4 mk0 = *(const f32x4*)&maskb[jc * 32 + g * 4];
        const f32x4 mk1 = *(const f32x4*)&maskb[jc * 32 + 16 + g * 4];

        // softmax numerator (no max subtraction; logits O(1), masked -> exp2(-1.5e9)=0)
#pragma unroll
        for (int it = 0; it < 4; ++it) {
            float p0[4], p1[4];
#pragma unroll
            for (int r = 0; r < 4; ++r) {
                p0[r] = exp2v(st[0][it][r] + pc0[it][r] + mk0[r]);
                p1[r] = exp2v(st[1][it][r] + pc1[it][r] + mk1[r]);
            }
#pragma unroll
            for (int r = 0; r < 4; ++r) lsum[it] += p0[r] + p1[r];
            const int row = w * 64 + it * 16 + l16;
            *(uint2*)&qp_s[swz32(row, g * 4)]      = make_uint2(cvtpk(p0[0], p0[1]), cvtpk(p0[2], p0[3]));
            *(uint2*)&qp_s[swz32(row, 16 + g * 4)] = make_uint2(cvtpk(p1[0], p1[1]), cvtpk(p1[2], p1[3]));
        }
        // PV: O^T += mfma(V^T, P)   (P round-trip is wave-private -> no barrier)
        __builtin_amdgcn_s_setprio(1);
#pragma unroll
        for (int it = 0; it < 4; ++it) {
            const bf16x8 bp = *(const bf16x8*)&qp_s[swz32(w * 64 + it * 16 + l16, g * 8)];
            oT[0][it] = mfma16(av[0], bp, oT[0][it]);
            oT[1][it] = mfma16(av[1], bp, oT[1][it]);
        }
        __builtin_amdgcn_s_setprio(0);

        if (jc < 7) {
#pragma unroll
            for (int jt = 0; jt < 2; ++jt) ak[jt] = akn[jt];
#pragma unroll
            for (int ct = 0; ct < 2; ++ct) av[ct] = avn[ct];
#pragma unroll
            for (int it = 0; it < 4; ++it) { pc0[it] = pn0[it]; pc1[it] = pn1[it]; }
        }
    }

    float inv[4];
#pragma unroll
    for (int it = 0; it < 4; ++it) {
        float s = lsum[it];
        s += __shfl_xor(s, 16, 64);
        s += __shfl_xor(s, 32, 64);
        inv[it] = rcpv(s);
    }

    __syncthreads();   // bar2: all waves done with k_s/vT/P -> buffers reusable

    // gate regs -> gateT[c][i] in qp_s (wave-private i-range; swzT keeps i in-range)
#pragma unroll
    for (int ct = 0; ct < 2; ++ct) {
        const int cc = ct * 16 + l16;
#pragma unroll
        for (int rt = 0; rt < 4; ++rt) {
            const int i0 = w * 64 + rt * 16 + g * 4;
            *(uint2*)&qp_s[swzT(cc, i0)] = gpk[ct][rt];
        }
    }
    // gating: read gateT (same-wave data, in-order DS), write gated output into k_s [c][i]
#pragma unroll
    for (int ct = 0; ct < 2; ++ct)
#pragma unroll
        for (int it = 0; it < 4; ++it) {
            const int i = w * 64 + it * 16 + l16;
#pragma unroll
            for (int r = 0; r < 4; ++r) {
                const int c = ct * 16 + g * 4 + r;
                const float gate = bflo((uint_t)qp_s[swzT(c, i)]);
                k_s[swzT(c, i)] = f2bf(oT[ct][it][r] * inv[it] * gate);
            }
        }
    __syncthreads();   // bar3: gated output complete
    // coalesced bf16x2 store to ao[n*256+i][h*32+c]
    ushort_t* aob = ao + (size_t)n * 256 * 256 + h * 32;
#pragma unroll
    for (int iter = 0; iter < 16; ++iter) {
        const int flat = iter * 256 + t;
        const int i = flat >> 4, cp = flat & 15;
        const uint_t lo = k_s[swzT(2 * cp, i)];
        const uint_t hi = k_s[swzT(2 * cp + 1, i)];
        *(uint_t*)(aob + (size_t)i * 256 + 2 * cp) = lo | (hi << 16);
    }
}

// -------- K4: out = ao @ Wo + bo (MFMA), row-masked --------
__global__ __launch_bounds__(256, 2) void k_out(const ushort_t* __restrict__ ao,
                                                const ushort_t* __restrict__ woT,
                                                const float* __restrict__ bo,
                                                const int* __restrict__ msa_mask,
                                                float* __restrict__ out) {
    const int t = threadIdx.x;
    const int rb = blockIdx.x * 128;
    const int w = t >> 6, l = t & 63;
    const int l16 = l & 15, g = l >> 4;

#pragma unroll
    for (int ch = 0; ch < 2; ++ch) {
        f32x4 acc[2][8];
#pragma unroll
        for (int rt = 0; rt < 2; ++rt)
#pragma unroll
            for (int ct = 0; ct < 8; ++ct) acc[rt][ct] = (f32x4){0.f, 0.f, 0.f, 0.f};
#pragma unroll
        for (int ks = 0; ks < 8; ++ks) {
            bf16x8 a[2], b[8];
#pragma unroll
            for (int rt = 0; rt < 2; ++rt)
                a[rt] = *(const bf16x8*)(ao + (size_t)(rb + w * 32 + rt * 16 + l16) * 256 + ks * 32 + g * 8);
#pragma unroll
            for (int ct = 0; ct < 8; ++ct)
                b[ct] = *(const bf16x8*)(woT + (size_t)(ch * 128 + ct * 16 + l16) * 256 + ks * 32 + g * 8);
#pragma unroll
            for (int rt = 0; rt < 2; ++rt)
#pragma unroll
                for (int ct = 0; ct < 8; ++ct)
                    acc[rt][ct] = mfma16(a[rt], b[ct], acc[rt][ct]);
        }
#pragma unroll
        for (int rt = 0; rt < 2; ++rt)
#pragma unroll
            for (int ct = 0; ct < 8; ++ct) {
                const int c = ch * 128 + ct * 16 + l16;
                const float boc = bo[c];
#pragma unroll
                for (int r = 0; r < 4; ++r) {
                    const int row = rb + w * 32 + rt * 16 + g * 4 + r;
                    const float mk = msa_mask[row] ? 1.f : 0.f;
                    out[(size_t)row * 256 + c] = (acc[rt][ct][r] + boc) * mk;
                }
            }
    }
}

extern "C" void kernel_launch(void* const* d_in, const int* in_sizes, int n_in,
                              void* d_out, int out_size, void* d_ws, size_t ws_size,
                              hipStream_t stream) {
    const float* m       = (const float*)d_in[0];
    const float* z       = (const float*)d_in[1];
    const int* msa_mask  = (const int*)d_in[2];
    const float* ln_m_g  = (const float*)d_in[3];
    const float* ln_m_b  = (const float*)d_in[4];
    const float* ln_z_g  = (const float*)d_in[5];
    const float* ln_z_b  = (const float*)d_in[6];
    const float* Wq      = (const float*)d_in[7];
    const float* Wk      = (const float*)d_in[8];
    const float* Wv      = (const float*)d_in[9];
    const float* Wb      = (const float*)d_in[10];
    const float* Wg      = (const float*)d_in[11];
    const float* bg      = (const float*)d_in[12];
    const float* Wo      = (const float*)d_in[13];
    const float* bo      = (const float*)d_in[14];
    float* out           = (float*)d_out;

    char* ws = (char*)d_ws;
    ushort_t* mn  = (ushort_t*)(ws);                    // 33,554,432 B
    float*    pb  = (float*)(ws + 33554432);            //  2,097,152 B
    ushort_t* ao  = (ushort_t*)(ws + 35651584);         // 33,554,432 B
    ushort_t* wtT = (ushort_t*)(ws + 69206016);         //    524,288 B
    ushort_t* woT = (ushort_t*)(ws + 69730304);         //    131,072 B

    k_pre<<<17664, 256, 0, stream>>>(m, ln_m_g, ln_m_b, z, ln_z_g, ln_z_b, Wb,
                                     Wq, Wk, Wv, Wg, Wo, mn, pb, wtT, woT);
    k_attn<<<2048, 256, 0, stream>>>(mn, wtT, pb, msa_mask, bg, ao);
    k_out<<<512, 256, 0, stream>>>(ao, woT, bo, msa_mask, out);
}

// Round 13
// 262.150 us; speedup vs baseline: 1.1119x; 1.1119x over previous
//
#include <hip/hip_runtime.h>

typedef unsigned short ushort_t;
typedef unsigned int uint_t;
typedef __attribute__((ext_vector_type(8))) short bf16x8;
typedef __attribute__((ext_vector_type(4))) float f32x4;

#define EPSV 1e-5f
#define LOG2E 1.4426950408889634f
#define QSC (0.17677669529663687f * LOG2E)   // (1/sqrt(32)) * log2(e)

__device__ __forceinline__ float u2f(uint_t x) { return __builtin_bit_cast(float, x); }
__device__ __forceinline__ uint_t f2u(float x) { return __builtin_bit_cast(uint_t, x); }
__device__ __forceinline__ float bflo(uint_t u) { return u2f(u << 16); }
__device__ __forceinline__ float bfhi(uint_t u) { return u2f(u & 0xFFFF0000u); }
__device__ __forceinline__ ushort_t f2bf(float f) {
    uint_t x = f2u(f);
    x += 0x7FFFu + ((x >> 16) & 1u);   // RNE
    return (ushort_t)(x >> 16);
}
__device__ __forceinline__ uint_t cvtpk(float lo, float hi) {
    uint_t r;
    asm("v_cvt_pk_bf16_f32 %0, %1, %2" : "=v"(r) : "v"(lo), "v"(hi));
    return r;
}
__device__ __forceinline__ float exp2v(float x) {
    float r;
    asm("v_exp_f32 %0, %1" : "=v"(r) : "v"(x));
    return r;
}
__device__ __forceinline__ float rcpv(float x) {
    float r;
    asm("v_rcp_f32 %0, %1" : "=v"(r) : "v"(x));
    return r;
}
__device__ __forceinline__ f32x4 mfma16(bf16x8 a, bf16x8 b, f32x4 c) {
    return __builtin_amdgcn_mfma_f32_16x16x32_bf16(a, b, c, 0, 0, 0);
}
__device__ __forceinline__ float wsum(float v) {
#pragma unroll
    for (int m = 32; m >= 1; m >>= 1) v += __shfl_xor(v, m, 64);
    return v;
}
// XOR swizzles (bijective; flip bits 3-5 of the linear ush index; keep 8-ush
// chunks intact so b128/uint2 accesses stay contiguous & aligned).
__device__ __forceinline__ int swz32(int row, int col) {   // [256][32] tiles
    return (row * 32 + col) ^ ((row & 7) << 3);
}
__device__ __forceinline__ int swzT(int c, int i) {        // [32][256] tiles
    return c * 256 + (i ^ ((c & 7) << 3));
}

// -------- K_pre: fused {LayerNorm(m) | LayerNorm(z)@Wb | weight transpose} --------
#define NB_LN 16384
#define NB_PB 1024
__global__ __launch_bounds__(256) void k_pre(const float* __restrict__ m,
                                             const float* __restrict__ ln_m_g,
                                             const float* __restrict__ ln_m_b,
                                             const float* __restrict__ z,
                                             const float* __restrict__ ln_z_g,
                                             const float* __restrict__ ln_z_b,
                                             const float* __restrict__ Wb,
                                             const float* __restrict__ Wq, const float* __restrict__ Wk,
                                             const float* __restrict__ Wv, const float* __restrict__ Wg,
                                             const float* __restrict__ Wo,
                                             ushort_t* __restrict__ mn,
                                             float* __restrict__ pb,
                                             ushort_t* __restrict__ wtT, ushort_t* __restrict__ woT) {
    __shared__ float wb_lds[1024];
    const int bid = blockIdx.x, t = threadIdx.x;

    if (bid < NB_LN) {
        const int lane = t & 63;
        const int row  = bid * 4 + (t >> 6);
        const float4 x = *(const float4*)(m + (size_t)row * 256 + lane * 4);
        const float mu = wsum(x.x + x.y + x.z + x.w) * (1.f / 256.f);
        const float dx = x.x - mu, dy = x.y - mu, dz = x.z - mu, dw = x.w - mu;
        const float var = wsum(dx * dx + dy * dy + dz * dz + dw * dw) * (1.f / 256.f);
        const float rs = rsqrtf(var + EPSV);
        const float4 gg = *(const float4*)(ln_m_g + lane * 4);
        const float4 bb = *(const float4*)(ln_m_b + lane * 4);
        ushort4 o;
        o.x = f2bf(dx * rs * gg.x + bb.x);
        o.y = f2bf(dy * rs * gg.y + bb.y);
        o.z = f2bf(dz * rs * gg.z + bb.z);
        o.w = f2bf(dw * rs * gg.w + bb.w);
        *(ushort4*)(mn + (size_t)row * 256 + lane * 4) = o;
    } else if (bid < NB_LN + NB_PB) {
        const int pbid = bid - NB_LN;
        const int w = t >> 6, l = t & 63;
        const int l16 = l & 15, gq = l >> 4;
        *(float4*)&wb_lds[t * 4] = *(const float4*)(Wb + t * 4);
        __syncthreads();

        const int row = pbid * 64 + w * 16 + l16;
        const float* zr = z + (size_t)row * 128;
        float v[32];
        float s1 = 0.f, s2 = 0.f;
#pragma unroll
        for (int ks = 0; ks < 4; ++ks) {
            const float4 a0 = *(const float4*)(zr + ks * 32 + gq * 8);
            const float4 a1 = *(const float4*)(zr + ks * 32 + gq * 8 + 4);
            v[ks * 8 + 0] = a0.x; v[ks * 8 + 1] = a0.y; v[ks * 8 + 2] = a0.z; v[ks * 8 + 3] = a0.w;
            v[ks * 8 + 4] = a1.x; v[ks * 8 + 5] = a1.y; v[ks * 8 + 6] = a1.z; v[ks * 8 + 7] = a1.w;
        }
#pragma unroll
        for (int j = 0; j < 32; ++j) { s1 += v[j]; s2 += v[j] * v[j]; }
        s1 += __shfl_xor(s1, 16, 64); s1 += __shfl_xor(s1, 32, 64);
        s2 += __shfl_xor(s2, 16, 64); s2 += __shfl_xor(s2, 32, 64);
        const float mu = s1 * (1.f / 128.f);
        const float var = s2 * (1.f / 128.f) - mu * mu;
        const float rs = rsqrtf(var + EPSV);

        f32x4 acc = (f32x4){0.f, 0.f, 0.f, 0.f};
#pragma unroll
        for (int ks = 0; ks < 4; ++ks) {
            const float4 g0 = *(const float4*)(ln_z_g + ks * 32 + gq * 8);
            const float4 g1 = *(const float4*)(ln_z_g + ks * 32 + gq * 8 + 4);
            const float4 b0 = *(const float4*)(ln_z_b + ks * 32 + gq * 8);
            const float4 b1 = *(const float4*)(ln_z_b + ks * 32 + gq * 8 + 4);
            const float xn0 = (v[ks * 8 + 0] - mu) * rs * g0.x + b0.x;
            const float xn1 = (v[ks * 8 + 1] - mu) * rs * g0.y + b0.y;
            const float xn2 = (v[ks * 8 + 2] - mu) * rs * g0.z + b0.z;
            const float xn3 = (v[ks * 8 + 3] - mu) * rs * g0.w + b0.w;
            const float xn4 = (v[ks * 8 + 4] - mu) * rs * g1.x + b1.x;
            const float xn5 = (v[ks * 8 + 5] - mu) * rs * g1.y + b1.y;
            const float xn6 = (v[ks * 8 + 6] - mu) * rs * g1.z + b1.z;
            const float xn7 = (v[ks * 8 + 7] - mu) * rs * g1.w + b1.w;
            uint4 pk;
            pk.x = cvtpk(xn0, xn1); pk.y = cvtpk(xn2, xn3);
            pk.z = cvtpk(xn4, xn5); pk.w = cvtpk(xn6, xn7);
            const bf16x8 af = __builtin_bit_cast(bf16x8, pk);
            ushort_t wf[8];
#pragma unroll
            for (int j = 0; j < 8; ++j)
                wf[j] = (l16 < 8) ? f2bf(wb_lds[(ks * 32 + gq * 8 + j) * 8 + l16]) : (ushort_t)0;
            const bf16x8 bf_ = *(const bf16x8*)wf;
            acc = mfma16(af, bf_, acc);
        }
        if (l16 < 8) {
            const int orow = pbid * 64 + w * 16 + gq * 4;
            f32x4 o;
            o[0] = acc[0] * LOG2E; o[1] = acc[1] * LOG2E;
            o[2] = acc[2] * LOG2E; o[3] = acc[3] * LOG2E;
            *(f32x4*)(pb + (size_t)l16 * 65536 + orow) = o;
        }
    } else {
        const int k = bid - (NB_LN + NB_PB);
        const int h = t >> 5, c = t & 31;
        wtT[(size_t)(h * 128 +   0 + c) * 256 + k] = f2bf(Wq[k * 256 + t]);
        wtT[(size_t)(h * 128 +  32 + c) * 256 + k] = f2bf(Wk[k * 256 + t]);
        wtT[(size_t)(h * 128 +  64 + c) * 256 + k] = f2bf(Wv[k * 256 + t]);
        wtT[(size_t)(h * 128 +  96 + c) * 256 + k] = f2bf(Wg[k * 256 + t]);
        woT[(size_t)t * 256 + k] = f2bf(Wo[k * 256 + t]);
    }
}

// -------- K3: MFMA fused QKVG projection + attention (no-max softmax) + gate --------
// R12's 50,176-B LDS layout (gate in regs; swizzled K/Q/P; swizzled vT) MINUS the
// depth-1 register pipeline (R8 proved it flat; R12 showed its ~64 prefetch regs
// pushed total VGPR+AGPR past the 2-waves/SIMD budget -> occupancy halved).
// Direct in-loop loads as in R5. min-waves MUST stay 1 (R7 A/B: (256,2) NaN'd).
// blockIdx decode: n = bid & 255, h = bid >> 8 => all 8 heads of one n land on the
// same XCD (XCD = bid % 8 = n % 8), so mn[n] is fetched from HBM once, reused from L2.
__global__ __launch_bounds__(256, 1) void k_attn(const ushort_t* __restrict__ mn,
                                                 const ushort_t* __restrict__ wtT,
                                                 const float* __restrict__ pb,
                                                 const int* __restrict__ msa_mask,
                                                 const float* __restrict__ bg,
                                                 ushort_t* __restrict__ ao) {
    __shared__ ushort_t k_s[8192];   // K [j][c] swz32; epilogue: gated-output [c][i] swzT
    __shared__ ushort_t qp_s[8192];  // q [i][c] swz32; Phase B: per-wave P; epilogue: gateT [c][i] swzT
    __shared__ ushort_t vT_s[8192];  // V^T [c][i] swzT
    __shared__ float maskb[256];

    const int t = threadIdx.x;
    const int n = blockIdx.x & 255, h = blockIdx.x >> 8;
    const int w = t >> 6, l = t & 63;
    const int l16 = l & 15, g = l >> 4;

    maskb[t] = msa_mask[n * 256 + t] ? 0.f : -1.5e9f;
    const float bg0 = bg[h * 32 + l16];
    const float bg1 = bg[h * 32 + 16 + l16];

    const ushort_t* mb = mn + (size_t)n * 65536;
    const ushort_t* wb = wtT + (size_t)h * 128 * 256;

    uint2 gpk[2][4];   // sigmoid gate, bf16-packed, in registers

    // ---- Phase A: qkvg[i][c] = mn[i][:] @ W[:,c] via MFMA ----
#pragma unroll
    for (int chalf = 0; chalf < 2; ++chalf) {
        f32x4 acc[4][4];
#pragma unroll
        for (int rt = 0; rt < 4; ++rt)
#pragma unroll
            for (int ct = 0; ct < 4; ++ct) acc[rt][ct] = (f32x4){0.f, 0.f, 0.f, 0.f};

#pragma unroll
        for (int ks = 0; ks < 8; ++ks) {
            bf16x8 a[4], b[4];
#pragma unroll
            for (int rt = 0; rt < 4; ++rt)
                a[rt] = *(const bf16x8*)(mb + (size_t)(w * 64 + rt * 16 + l16) * 256 + ks * 32 + g * 8);
#pragma unroll
            for (int ct = 0; ct < 4; ++ct)
                b[ct] = *(const bf16x8*)(wb + (size_t)(chalf * 64 + ct * 16 + l16) * 256 + ks * 32 + g * 8);
#pragma unroll
            for (int rt = 0; rt < 4; ++rt)
#pragma unroll
                for (int ct = 0; ct < 4; ++ct)
                    acc[rt][ct] = mfma16(a[rt], b[ct], acc[rt][ct]);
        }
        // epilogue: C-frag lane holds [row = g*4+r][col = l16]
#pragma unroll
        for (int ct = 0; ct < 4; ++ct) {
            const int mat = chalf * 2 + (ct >> 1);       // 0 q, 1 k, 2 v, 3 g
            const int cc = (ct & 1) * 16 + l16;
#pragma unroll
            for (int rt = 0; rt < 4; ++rt) {
                const int i0 = w * 64 + rt * 16 + g * 4;
                const f32x4 v = acc[rt][ct];
                if (mat == 0) {          // q: fold SCALE*log2e
#pragma unroll
                    for (int r = 0; r < 4; ++r) qp_s[swz32(i0 + r, cc)] = f2bf(v[r] * QSC);
                } else if (mat == 1) {   // k
#pragma unroll
                    for (int r = 0; r < 4; ++r) k_s[swz32(i0 + r, cc)] = f2bf(v[r]);
                } else if (mat == 2) {   // v -> transposed (swizzled)
                    *(uint2*)&vT_s[swzT(cc, i0)] = make_uint2(cvtpk(v[0], v[1]), cvtpk(v[2], v[3]));
                } else {                 // g -> sigmoid gate, kept in registers
                    const float bgc = (ct & 1) ? bg1 : bg0;
                    float gt[4];
#pragma unroll
                    for (int r = 0; r < 4; ++r)
                        gt[r] = rcpv(1.f + exp2v(-(v[r] + bgc) * LOG2E));
                    gpk[ct & 1][rt] = make_uint2(cvtpk(gt[0], gt[1]), cvtpk(gt[2], gt[3]));
                }
            }
        }
    }
    __syncthreads();   // bar1: q/k/vT visible to all waves

    // ---- Phase B: attention. Wave w owns rows i in [w*64, w*64+64). ----
    bf16x8 bq[4];
#pragma unroll
    for (int it = 0; it < 4; ++it)
        bq[it] = *(const bf16x8*)&qp_s[swz32(w * 64 + it * 16 + l16, g * 8)];
    // P buffer aliases this wave's own q rows (same-wave producer/consumer)

    const float* pbh = pb + (size_t)h * 65536;
    f32x4 oT[2][4];
#pragma unroll
    for (int ct = 0; ct < 2; ++ct)
#pragma unroll
        for (int it = 0; it < 4; ++it) oT[ct][it] = (f32x4){0.f, 0.f, 0.f, 0.f};
    float lsum[4] = {0.f, 0.f, 0.f, 0.f};

    for (int jc = 0; jc < 8; ++jc) {
        // issue pair-bias loads early (L2 latency hides under S-MFMAs)
        f32x4 pc0[4], pc1[4];
#pragma unroll
        for (int it = 0; it < 4; ++it) {
            const int i = w * 64 + it * 16 + l16;
            pc0[it] = *(const f32x4*)(pbh + (size_t)i * 256 + jc * 32 + g * 4);
            pc1[it] = *(const f32x4*)(pbh + (size_t)i * 256 + jc * 32 + 16 + g * 4);
        }
        bf16x8 ak[2], av[2];
#pragma unroll
        for (int jt = 0; jt < 2; ++jt)
            ak[jt] = *(const bf16x8*)&k_s[swz32(jc * 32 + jt * 16 + l16, g * 8)];
#pragma unroll
        for (int ct = 0; ct < 2; ++ct)
            av[ct] = *(const bf16x8*)&vT_s[swzT(ct * 16 + l16, jc * 32 + g * 8)];

        // S^T = mfma(K, Q): lane holds S[j = jc*32 + jt*16 + g*4 + r][i = it*16 + l16]
        f32x4 st[2][4];
        __builtin_amdgcn_s_setprio(1);
#pragma unroll
        for (int jt = 0; jt < 2; ++jt)
#pragma unroll
            for (int it = 0; it < 4; ++it)
                st[jt][it] = mfma16(ak[jt], bq[it], (f32x4){0.f, 0.f, 0.f, 0.f});
        __builtin_amdgcn_s_setprio(0);

        const f32x4 mk0 = *(const f32x4*)&maskb[jc * 32 + g * 4];
        const f32x4 mk1 = *(const f32x4*)&maskb[jc * 32 + 16 + g * 4];

        // softmax numerator (no max subtraction; logits O(1), masked -> exp2(-1.5e9)=0)
#pragma unroll
        for (int it = 0; it < 4; ++it) {
            float p0[4], p1[4];
#pragma unroll
            for (int r = 0; r < 4; ++r) {
                p0[r] = exp2v(st[0][it][r] + pc0[it][r] + mk0[r]);
                p1[r] = exp2v(st[1][it][r] + pc1[it][r] + mk1[r]);
            }
#pragma unroll
            for (int r = 0; r < 4; ++r) lsum[it] += p0[r] + p1[r];
            const int row = w * 64 + it * 16 + l16;
            *(uint2*)&qp_s[swz32(row, g * 4)]      = make_uint2(cvtpk(p0[0], p0[1]), cvtpk(p0[2], p0[3]));
            *(uint2*)&qp_s[swz32(row, 16 + g * 4)] = make_uint2(cvtpk(p1[0], p1[1]), cvtpk(p1[2], p1[3]));
        }
        // PV: O^T += mfma(V^T, P)   (P round-trip is wave-private -> no barrier)
        __builtin_amdgcn_s_setprio(1);
#pragma unroll
        for (int it = 0; it < 4; ++it) {
            const bf16x8 bp = *(const bf16x8*)&qp_s[swz32(w * 64 + it * 16 + l16, g * 8)];
            oT[0][it] = mfma16(av[0], bp, oT[0][it]);
            oT[1][it] = mfma16(av[1], bp, oT[1][it]);
        }
        __builtin_amdgcn_s_setprio(0);
    }

    float inv[4];
#pragma unroll
    for (int it = 0; it < 4; ++it) {
        float s = lsum[it];
        s += __shfl_xor(s, 16, 64);
        s += __shfl_xor(s, 32, 64);
        inv[it] = rcpv(s);
    }

    __syncthreads();   // bar2: all waves done with k_s/vT/P -> buffers reusable

    // gate regs -> gateT[c][i] in qp_s (wave-private i-range; swzT keeps i in-range)
#pragma unroll
    for (int ct = 0; ct < 2; ++ct) {
        const int cc = ct * 16 + l16;
#pragma unroll
        for (int rt = 0; rt < 4; ++rt) {
            const int i0 = w * 64 + rt * 16 + g * 4;
            *(uint2*)&qp_s[swzT(cc, i0)] = gpk[ct][rt];
        }
    }
    // gating: read gateT (same-wave data, in-order DS), write gated output into k_s [c][i]
#pragma unroll
    for (int ct = 0; ct < 2; ++ct)
#pragma unroll
        for (int it = 0; it < 4; ++it) {
            const int i = w * 64 + it * 16 + l16;
#pragma unroll
            for (int r = 0; r < 4; ++r) {
                const int c = ct * 16 + g * 4 + r;
                const float gate = bflo((uint_t)qp_s[swzT(c, i)]);
                k_s[swzT(c, i)] = f2bf(oT[ct][it][r] * inv[it] * gate);
            }
        }
    __syncthreads();   // bar3: gated output complete
    // coalesced bf16x2 store to ao[n*256+i][h*32+c]
    ushort_t* aob = ao + (size_t)n * 256 * 256 + h * 32;
#pragma unroll
    for (int iter = 0; iter < 16; ++iter) {
        const int flat = iter * 256 + t;
        const int i = flat >> 4, cp = flat & 15;
        const uint_t lo = k_s[swzT(2 * cp, i)];
        const uint_t hi = k_s[swzT(2 * cp + 1, i)];
        *(uint_t*)(aob + (size_t)i * 256 + 2 * cp) = lo | (hi << 16);
    }
}

// -------- K4: out = ao @ Wo + bo (MFMA), row-masked --------
__global__ __launch_bounds__(256, 2) void k_out(const ushort_t* __restrict__ ao,
                                                const ushort_t* __restrict__ woT,
                                                const float* __restrict__ bo,
                                                const int* __restrict__ msa_mask,
                                                float* __restrict__ out) {
    const int t = threadIdx.x;
    const int rb = blockIdx.x * 128;
    const int w = t >> 6, l = t & 63;
    const int l16 = l & 15, g = l >> 4;

#pragma unroll
    for (int ch = 0; ch < 2; ++ch) {
        f32x4 acc[2][8];
#pragma unroll
        for (int rt = 0; rt < 2; ++rt)
#pragma unroll
            for (int ct = 0; ct < 8; ++ct) acc[rt][ct] = (f32x4){0.f, 0.f, 0.f, 0.f};
#pragma unroll
        for (int ks = 0; ks < 8; ++ks) {
            bf16x8 a[2], b[8];
#pragma unroll
            for (int rt = 0; rt < 2; ++rt)
                a[rt] = *(const bf16x8*)(ao + (size_t)(rb + w * 32 + rt * 16 + l16) * 256 + ks * 32 + g * 8);
#pragma unroll
            for (int ct = 0; ct < 8; ++ct)
                b[ct] = *(const bf16x8*)(woT + (size_t)(ch * 128 + ct * 16 + l16) * 256 + ks * 32 + g * 8);
#pragma unroll
            for (int rt = 0; rt < 2; ++rt)
#pragma unroll
                for (int ct = 0; ct < 8; ++ct)
                    acc[rt][ct] = mfma16(a[rt], b[ct], acc[rt][ct]);
        }
#pragma unroll
        for (int rt = 0; rt < 2; ++rt)
#pragma unroll
            for (int ct = 0; ct < 8; ++ct) {
                const int c = ch * 128 + ct * 16 + l16;
                const float boc = bo[c];
#pragma unroll
                for (int r = 0; r < 4; ++r) {
                    const int row = rb + w * 32 + rt * 16 + g * 4 + r;
                    const float mk = msa_mask[row] ? 1.f : 0.f;
                    out[(size_t)row * 256 + c] = (acc[rt][ct][r] + boc) * mk;
                }
            }
    }
}

extern "C" void kernel_launch(void* const* d_in, const int* in_sizes, int n_in,
                              void* d_out, int out_size, void* d_ws, size_t ws_size,
                              hipStream_t stream) {
    const float* m       = (const float*)d_in[0];
    const float* z       = (const float*)d_in[1];
    const int* msa_mask  = (const int*)d_in[2];
    const float* ln_m_g  = (const float*)d_in[3];
    const float* ln_m_b  = (const float*)d_in[4];
    const float* ln_z_g  = (const float*)d_in[5];
    const float* ln_z_b  = (const float*)d_in[6];
    const float* Wq      = (const float*)d_in[7];
    const float* Wk      = (const float*)d_in[8];
    const float* Wv      = (const float*)d_in[9];
    const float* Wb      = (const float*)d_in[10];
    const float* Wg      = (const float*)d_in[11];
    const float* bg      = (const float*)d_in[12];
    const float* Wo      = (const float*)d_in[13];
    const float* bo      = (const float*)d_in[14];
    float* out           = (float*)d_out;

    char* ws = (char*)d_ws;
    ushort_t* mn  = (ushort_t*)(ws);                    // 33,554,432 B
    float*    pb  = (float*)(ws + 33554432);            //  2,097,152 B
    ushort_t* ao  = (ushort_t*)(ws + 35651584);         // 33,554,432 B
    ushort_t* wtT = (ushort_t*)(ws + 69206016);         //    524,288 B
    ushort_t* woT = (ushort_t*)(ws + 69730304);         //    131,072 B

    k_pre<<<17664, 256, 0, stream>>>(m, ln_m_g, ln_m_b, z, ln_z_g, ln_z_b, Wb,
                                     Wq, Wk, Wv, Wg, Wo, mn, pb, wtT, woT);
    k_attn<<<2048, 256, 0, stream>>>(mn, wtT, pb, msa_mask, bg, ao);
    k_out<<<512, 256, 0, stream>>>(ao, woT, bo, msa_mask, out);
}